// Round 6
// baseline (185.385 us; speedup 1.0000x reference)
//
#include <hip/hip_runtime.h>

// SmoothL1 (beta=0.5) masked sum reduction, N = 16M fixed.
// sl1 = ad < 0.5 ? d*d : ad - 0.25  (0.5*d*d/0.5 == d*d exactly: pow-2)
// mask: ad >= 1.0f/len; out[0] = sum(mask ? sl1 : 0)
//
// Ladder: plain=73us | sc1/sc0sc1=74-75us | nt d1=51us | nt d2=45.6us |
// nt d3=44.6us (4.5 TB/s; depth2->3 +2% => MLP saturated). R9 path-split
// regressed (L2 machinery throttles globally). FETCH_SIZE always exactly
// half -> counter artifact; full 192 MiB streams every launch.
//
// R11: SPATIAL INTERLEAVE. Block-contiguous layout = 6144 lock-step 1KB
// cursors at 32KB stride -> instantaneous channel front is bunched and
// phase-locked (all blocks start together, same pipeline). Grid-stride
// layout makes the instantaneous front CONTIGUOUS (~32MB dense window per
// stream): uniform channel/row coverage by construction, hash-independent.
// Same GRID/BLOCK/ITERS/depth/policy -- purely spatial change.
// NOTE: regroups per-thread partials (FP order changes). This round also
// probes the harness absmax tolerance for geometry changes.
// Predict: imbalance-wall -> 36-40us warm; neutral -> 44-46us (ceiling
// argument complete); failed -> tolerance is bit-exact, geometry frozen.

#define N_TOTAL 16777216
#define NVEC    (N_TOTAL / 4)       // 4194304 vec4 groups
#define BLOCK   256
#define GRID    2048                // 8 blocks/CU, 32 waves/CU
#define ITERS   (NVEC / (BLOCK * GRID))   // 8 iterations/thread, exact cover
#define STRIDE  (BLOCK * GRID)            // grid-stride in vec4 groups

typedef float f32x4 __attribute__((ext_vector_type(4)));
typedef int   i32x4 __attribute__((ext_vector_type(4)));

__device__ __forceinline__ float sl1_term(float o, float l, int len) {
    float d  = o - l;
    float ad = fabsf(d);
    float v  = (ad < 0.5f) ? (d * d) : (ad - 0.25f);
    float boundary = 1.0f / (float)len;   // IEEE divide; matches jnp 1/len
    return (ad >= boundary) ? v : 0.0f;
}

__device__ __forceinline__ float consume4(f32x4 o, f32x4 l, i32x4 n) {
    float s = 0.0f;
    s += sl1_term(o.x, l.x, n.x);
    s += sl1_term(o.y, l.y, n.y);
    s += sl1_term(o.z, l.z, n.z);
    s += sl1_term(o.w, l.w, n.w);
    return s;
}

__global__ __launch_bounds__(BLOCK, 8) void RegressionLoss_45440753992375_kernel(
        const float* __restrict__ outs,
        const float* __restrict__ labels,
        const int*   __restrict__ lens,
        float* __restrict__ out) {
    const f32x4* o4 = (const f32x4*)outs;
    const f32x4* l4 = (const f32x4*)labels;
    const i32x4* n4 = (const i32x4*)lens;

    // Grid-stride: iteration it touches the contiguous window
    // [it*STRIDE, (it+1)*STRIDE) -- dense global access front.
    const int base = blockIdx.x * BLOCK + threadIdx.x;

    // Pipeline prologue: iterations 0,1,2 in flight (9 loads).
    f32x4 oA = __builtin_nontemporal_load(o4 + base);
    f32x4 lA = __builtin_nontemporal_load(l4 + base);
    i32x4 nA = __builtin_nontemporal_load(n4 + base);

    f32x4 oB = __builtin_nontemporal_load(o4 + base + STRIDE);
    f32x4 lB = __builtin_nontemporal_load(l4 + base + STRIDE);
    i32x4 nB = __builtin_nontemporal_load(n4 + base + STRIDE);

    f32x4 oC = __builtin_nontemporal_load(o4 + base + 2 * STRIDE);
    f32x4 lC = __builtin_nontemporal_load(l4 + base + 2 * STRIDE);
    i32x4 nC = __builtin_nontemporal_load(n4 + base + 2 * STRIDE);

    float acc = 0.0f;
    #pragma unroll
    for (int it = 0; it < ITERS - 3; ++it) {
        // Issue iteration it+3 (12 outstanding) before consuming iteration it.
        const int idx = base + (it + 3) * STRIDE;
        f32x4 oD = __builtin_nontemporal_load(o4 + idx);
        f32x4 lD = __builtin_nontemporal_load(l4 + idx);
        i32x4 nD = __builtin_nontemporal_load(n4 + idx);

        acc += consume4(oA, lA, nA);

        // Rotate stages (register renaming; loop fully unrolled).
        oA = oB; lA = lB; nA = nB;
        oB = oC; lB = lC; nB = nC;
        oC = oD; lC = lD; nC = nD;
    }
    acc += consume4(oA, lA, nA);   // iteration ITERS-3
    acc += consume4(oB, lB, nB);   // iteration ITERS-2
    acc += consume4(oC, lC, nC);   // iteration ITERS-1

    // wave-64 shuffle reduction
    #pragma unroll
    for (int off = 32; off > 0; off >>= 1)
        acc += __shfl_down(acc, off, 64);

    __shared__ float smem[BLOCK / 64];
    const int lane = threadIdx.x & 63;
    const int wid  = threadIdx.x >> 6;
    if (lane == 0) smem[wid] = acc;
    __syncthreads();
    if (threadIdx.x == 0) {
        float bsum = smem[0] + smem[1] + smem[2] + smem[3];
        atomicAdd(out, bsum);   // device-scope by default on CDNA
    }
}

extern "C" void kernel_launch(void* const* d_in, const int* in_sizes, int n_in,
                              void* d_out, int out_size, void* d_ws, size_t ws_size,
                              hipStream_t stream) {
    const float* outs   = (const float*)d_in[0];
    const float* labels = (const float*)d_in[1];
    const int*   lens   = (const int*)d_in[2];
    float* out = (float*)d_out;

    // d_out is poisoned 0xAA before every timed launch — zero it on-stream.
    hipMemsetAsync(out, 0, sizeof(float), stream);

    RegressionLoss_45440753992375_kernel<<<GRID, BLOCK, 0, stream>>>(outs, labels, lens, out);
}

// Round 7
// 184.306 us; speedup vs baseline: 1.0059x; 1.0059x over previous
//
#include <hip/hip_runtime.h>

// SmoothL1 (beta=0.5) masked sum reduction, N = 16M fixed.
// sl1 = ad < 0.5 ? d*d : ad - 0.25  (0.5*d*d/0.5 == d*d exactly: pow-2)
// mask: ad >= 1.0f/len; out[0] = sum(mask ? sl1 : 0)
//
// Ladder: plain=73 | sc1/sc0sc1=74-75 | nt d1=51 | nt d2=45.6 | nt d3=44.6us
// (4.5 TB/s, MLP saturated) | R9 lens-via-L2=52 (L2 machinery global) |
// R11 grid-stride=50 (REGRESS: per-cursor locality matters; 32MB jumps break
// row-buffer/page sequentiality). FETCH_SIZE always exactly half -> artifact.
//
// R12: PHASE ROTATION — the untested {locality x coverage} cell.
// R10 front: {b*32KB + it*4KB}, 1/8-duty periodic, phase-locked across
// blocks -> partial channel coverage if interleave period ~32KB.
// R11 had coverage but no locality. Here: block b visits its 8 chunks in
// order (it+b)%8 -> instantaneous front covers all 8 sub-offsets uniformly
// (b spans all residues) while each block still walks 4KB-sequential steps
// (one wrap per kernel). Depth-3 pipeline, policy, grid unchanged.
// Predict: phase-wall -> 34-38us warm; neutral -> 44-46us and the ladder is
// exhausted (declare nt-path roofline); >=48us -> rotation broke prefetch.

#define N_TOTAL 16777216
#define NVEC    (N_TOTAL / 4)       // 4194304 vec4 groups
#define BLOCK   256
#define GRID    2048                // 8 blocks/CU, 32 waves/CU
#define ITERS   (NVEC / (BLOCK * GRID))   // 8 iterations/thread, exact cover

typedef float f32x4 __attribute__((ext_vector_type(4)));
typedef int   i32x4 __attribute__((ext_vector_type(4)));

__device__ __forceinline__ float sl1_term(float o, float l, int len) {
    float d  = o - l;
    float ad = fabsf(d);
    float v  = (ad < 0.5f) ? (d * d) : (ad - 0.25f);
    float boundary = 1.0f / (float)len;   // IEEE divide; matches jnp 1/len
    return (ad >= boundary) ? v : 0.0f;
}

__device__ __forceinline__ float consume4(f32x4 o, f32x4 l, i32x4 n) {
    float s = 0.0f;
    s += sl1_term(o.x, l.x, n.x);
    s += sl1_term(o.y, l.y, n.y);
    s += sl1_term(o.z, l.z, n.z);
    s += sl1_term(o.w, l.w, n.w);
    return s;
}

__global__ __launch_bounds__(BLOCK, 8) void RegressionLoss_45440753992375_kernel(
        const float* __restrict__ outs,
        const float* __restrict__ labels,
        const int*   __restrict__ lens,
        float* __restrict__ out) {
    const f32x4* o4 = (const f32x4*)outs;
    const f32x4* l4 = (const f32x4*)labels;
    const i32x4* n4 = (const i32x4*)lens;

    // Block-contiguous span; iteration j visits chunk (start+j)%8 of the span.
    const int base  = blockIdx.x * (BLOCK * ITERS) + threadIdx.x;
    const int start = blockIdx.x & (ITERS - 1);   // per-block phase rotation

    #define IDX(j) (base + (((start + (j)) & (ITERS - 1)) * BLOCK))

    // Pipeline prologue: rotated iterations 0,1,2 in flight (9 loads).
    f32x4 oA = __builtin_nontemporal_load(o4 + IDX(0));
    f32x4 lA = __builtin_nontemporal_load(l4 + IDX(0));
    i32x4 nA = __builtin_nontemporal_load(n4 + IDX(0));

    f32x4 oB = __builtin_nontemporal_load(o4 + IDX(1));
    f32x4 lB = __builtin_nontemporal_load(l4 + IDX(1));
    i32x4 nB = __builtin_nontemporal_load(n4 + IDX(1));

    f32x4 oC = __builtin_nontemporal_load(o4 + IDX(2));
    f32x4 lC = __builtin_nontemporal_load(l4 + IDX(2));
    i32x4 nC = __builtin_nontemporal_load(n4 + IDX(2));

    float acc = 0.0f;
    #pragma unroll
    for (int it = 0; it < ITERS - 3; ++it) {
        // Issue rotated iteration it+3 (12 outstanding) before consuming it.
        const int idx = IDX(it + 3);
        f32x4 oD = __builtin_nontemporal_load(o4 + idx);
        f32x4 lD = __builtin_nontemporal_load(l4 + idx);
        i32x4 nD = __builtin_nontemporal_load(n4 + idx);

        acc += consume4(oA, lA, nA);

        // Rotate stages (register renaming; loop fully unrolled).
        oA = oB; lA = lB; nA = nB;
        oB = oC; lB = lC; nB = nC;
        oC = oD; lC = lD; nC = nD;
    }
    acc += consume4(oA, lA, nA);   // rotated iteration ITERS-3
    acc += consume4(oB, lB, nB);   // rotated iteration ITERS-2
    acc += consume4(oC, lC, nC);   // rotated iteration ITERS-1

    #undef IDX

    // wave-64 shuffle reduction
    #pragma unroll
    for (int off = 32; off > 0; off >>= 1)
        acc += __shfl_down(acc, off, 64);

    __shared__ float smem[BLOCK / 64];
    const int lane = threadIdx.x & 63;
    const int wid  = threadIdx.x >> 6;
    if (lane == 0) smem[wid] = acc;
    __syncthreads();
    if (threadIdx.x == 0) {
        float bsum = smem[0] + smem[1] + smem[2] + smem[3];
        atomicAdd(out, bsum);   // device-scope by default on CDNA
    }
}

extern "C" void kernel_launch(void* const* d_in, const int* in_sizes, int n_in,
                              void* d_out, int out_size, void* d_ws, size_t ws_size,
                              hipStream_t stream) {
    const float* outs   = (const float*)d_in[0];
    const float* labels = (const float*)d_in[1];
    const int*   lens   = (const int*)d_in[2];
    float* out = (float*)d_out;

    // d_out is poisoned 0xAA before every timed launch — zero it on-stream.
    hipMemsetAsync(out, 0, sizeof(float), stream);

    RegressionLoss_45440753992375_kernel<<<GRID, BLOCK, 0, stream>>>(outs, labels, lens, out);
}

// Round 8
// 178.615 us; speedup vs baseline: 1.0379x; 1.0319x over previous
//
#include <hip/hip_runtime.h>

// SmoothL1 (beta=0.5) masked sum reduction, N = 16M fixed.
// sl1 = ad < 0.5 ? d*d : ad - 0.25  (0.5*d*d/0.5 == d*d exactly: pow-2)
// mask: ad >= 1.0f/len; out[0] = sum(mask ? sl1 : 0)
//
// Ladder: plain=73 | sc1/sc0sc1=74-75 | nt d1=51 | nt d2=45.6 | nt d3=44.6us
// (4.5 TB/s) | R9 lens-via-L2=52 (global L2 throttle) | R11 grid-stride=50
// (locality loss) | R12 phase-rotation=44.3 (NEUTRAL: channel coverage not
// the wall). FETCH_SIZE exactly half everywhere -> counter artifact.
//
// R13: CURSOR-COUNT x RUN-LENGTH — the last untested structural axis.
// All prior configs: 6144 cursors x 32KB spans (4KB steps). Here: halve
// cursors (GRID=1024, 3072 cursors), double run length (64KB spans, 16x4KB
// sequential steps), deepen pipeline to 6 so device-wide bytes-in-flight
// stays comparable (~75MB vs R10's ~100MB). launch_bounds(256,4): up to
// 128 VGPR without dropping the 16-wave/CU config.
// Predict: DRAM-page wall -> 40-42us; request-capacity wall -> 46-49us;
// neutral -> 44-46us. PRE-COMMIT: neutral/regress => declare nt-path
// roofline next round (all articulable axes falsified).

#define N_TOTAL 16777216
#define NVEC    (N_TOTAL / 4)       // 4194304 vec4 groups
#define BLOCK   256
#define GRID    1024                // 4 blocks/CU, 16 waves/CU
#define ITERS   (NVEC / (BLOCK * GRID))   // 16 iterations/thread, exact cover

typedef float f32x4 __attribute__((ext_vector_type(4)));
typedef int   i32x4 __attribute__((ext_vector_type(4)));

__device__ __forceinline__ float sl1_term(float o, float l, int len) {
    float d  = o - l;
    float ad = fabsf(d);
    float v  = (ad < 0.5f) ? (d * d) : (ad - 0.25f);
    float boundary = 1.0f / (float)len;   // IEEE divide; matches jnp 1/len
    return (ad >= boundary) ? v : 0.0f;
}

__device__ __forceinline__ float consume4(f32x4 o, f32x4 l, i32x4 n) {
    float s = 0.0f;
    s += sl1_term(o.x, l.x, n.x);
    s += sl1_term(o.y, l.y, n.y);
    s += sl1_term(o.z, l.z, n.z);
    s += sl1_term(o.w, l.w, n.w);
    return s;
}

__global__ __launch_bounds__(BLOCK, 4) void RegressionLoss_45440753992375_kernel(
        const float* __restrict__ outs,
        const float* __restrict__ labels,
        const int*   __restrict__ lens,
        float* __restrict__ out) {
    const f32x4* o4 = (const f32x4*)outs;
    const f32x4* l4 = (const f32x4*)labels;
    const i32x4* n4 = (const i32x4*)lens;

    // Block-contiguous 64KB span per array; thread strides BLOCK (4KB steps).
    const int base = blockIdx.x * (BLOCK * ITERS) + threadIdx.x;

    // Pipeline prologue: iterations 0..5 in flight (18 loads, 288B/thread).
    f32x4 oA = __builtin_nontemporal_load(o4 + base);
    f32x4 lA = __builtin_nontemporal_load(l4 + base);
    i32x4 nA = __builtin_nontemporal_load(n4 + base);

    f32x4 oB = __builtin_nontemporal_load(o4 + base + 1 * BLOCK);
    f32x4 lB = __builtin_nontemporal_load(l4 + base + 1 * BLOCK);
    i32x4 nB = __builtin_nontemporal_load(n4 + base + 1 * BLOCK);

    f32x4 oC = __builtin_nontemporal_load(o4 + base + 2 * BLOCK);
    f32x4 lC = __builtin_nontemporal_load(l4 + base + 2 * BLOCK);
    i32x4 nC = __builtin_nontemporal_load(n4 + base + 2 * BLOCK);

    f32x4 oD = __builtin_nontemporal_load(o4 + base + 3 * BLOCK);
    f32x4 lD = __builtin_nontemporal_load(l4 + base + 3 * BLOCK);
    i32x4 nD = __builtin_nontemporal_load(n4 + base + 3 * BLOCK);

    f32x4 oE = __builtin_nontemporal_load(o4 + base + 4 * BLOCK);
    f32x4 lE = __builtin_nontemporal_load(l4 + base + 4 * BLOCK);
    i32x4 nE = __builtin_nontemporal_load(n4 + base + 4 * BLOCK);

    f32x4 oF = __builtin_nontemporal_load(o4 + base + 5 * BLOCK);
    f32x4 lF = __builtin_nontemporal_load(l4 + base + 5 * BLOCK);
    i32x4 nF = __builtin_nontemporal_load(n4 + base + 5 * BLOCK);

    float acc = 0.0f;
    #pragma unroll
    for (int it = 0; it < ITERS - 6; ++it) {
        // Issue iteration it+6 (21 outstanding peak) before consuming it.
        const int idx = base + (it + 6) * BLOCK;
        f32x4 oG = __builtin_nontemporal_load(o4 + idx);
        f32x4 lG = __builtin_nontemporal_load(l4 + idx);
        i32x4 nG = __builtin_nontemporal_load(n4 + idx);

        acc += consume4(oA, lA, nA);

        // Rotate stages (register renaming; loop fully unrolled).
        oA = oB; lA = lB; nA = nB;
        oB = oC; lB = lC; nB = nC;
        oC = oD; lC = lD; nC = nD;
        oD = oE; lD = lE; nD = nE;
        oE = oF; lE = lF; nE = nF;
        oF = oG; lF = lG; nF = nG;
    }
    acc += consume4(oA, lA, nA);   // iteration ITERS-6
    acc += consume4(oB, lB, nB);   // iteration ITERS-5
    acc += consume4(oC, lC, nC);   // iteration ITERS-4
    acc += consume4(oD, lD, nD);   // iteration ITERS-3
    acc += consume4(oE, lE, nE);   // iteration ITERS-2
    acc += consume4(oF, lF, nF);   // iteration ITERS-1

    // wave-64 shuffle reduction
    #pragma unroll
    for (int off = 32; off > 0; off >>= 1)
        acc += __shfl_down(acc, off, 64);

    __shared__ float smem[BLOCK / 64];
    const int lane = threadIdx.x & 63;
    const int wid  = threadIdx.x >> 6;
    if (lane == 0) smem[wid] = acc;
    __syncthreads();
    if (threadIdx.x == 0) {
        float bsum = smem[0] + smem[1] + smem[2] + smem[3];
        atomicAdd(out, bsum);   // device-scope by default on CDNA
    }
}

extern "C" void kernel_launch(void* const* d_in, const int* in_sizes, int n_in,
                              void* d_out, int out_size, void* d_ws, size_t ws_size,
                              hipStream_t stream) {
    const float* outs   = (const float*)d_in[0];
    const float* labels = (const float*)d_in[1];
    const int*   lens   = (const int*)d_in[2];
    float* out = (float*)d_out;

    // d_out is poisoned 0xAA before every timed launch — zero it on-stream.
    hipMemsetAsync(out, 0, sizeof(float), stream);

    RegressionLoss_45440753992375_kernel<<<GRID, BLOCK, 0, stream>>>(outs, labels, lens, out);
}

// Round 9
// 175.981 us; speedup vs baseline: 1.0534x; 1.0150x over previous
//
#include <hip/hip_runtime.h>

// SmoothL1 (beta=0.5) masked sum reduction, N = 16M fixed.
// sl1 = ad < 0.5 ? d*d : ad - 0.25  (0.5*d*d/0.5 == d*d exactly: pow-2)
// mask: ad >= 1.0f/len; out[0] = sum(mask ? sl1 : 0)
//
// Ladder: plain=73 | sc1=74-75 | nt d1=51 | nt d2=45.6 | nt d3=44.6 (6144
// cursors x 32KB) | R9 lens-via-L2=52 | R11 grid-stride=50 | R12 phase-rot=
// 44.3 (neutral) | R13 3072 cursors x 64KB runs + depth6 = <40us (dropped
// below the 40.2us poison-fills; bench 182.8->178.6). Harness fill kernel
// sustains 6.7 TB/s pure-write -> long-run streaming ceiling is ~6.6 TB/s;
// our ~5.0 TB/s read has headroom. NOT roofline yet.
//
// R14: continue the cursor axis, single-variable: GRID 1024->512 (1536
// cursors x 128KB sequential runs), ITERS=32, depth stays 6. TLP check:
// 38MB device-wide in flight >> ~9MB Little's-law need at 6 TB/s.
// Predict: page-wall continues -> 36-38us warm; passed balance point ->
// 42-46us; neutral -> axis saturated, fall back to R13 config.
// Per-thread element order unchanged within each thread's span walk.

#define N_TOTAL 16777216
#define NVEC    (N_TOTAL / 4)       // 4194304 vec4 groups
#define BLOCK   256
#define GRID    512                 // 2 blocks/CU, 8 waves/CU
#define ITERS   (NVEC / (BLOCK * GRID))   // 32 iterations/thread, exact cover

typedef float f32x4 __attribute__((ext_vector_type(4)));
typedef int   i32x4 __attribute__((ext_vector_type(4)));

__device__ __forceinline__ float sl1_term(float o, float l, int len) {
    float d  = o - l;
    float ad = fabsf(d);
    float v  = (ad < 0.5f) ? (d * d) : (ad - 0.25f);
    float boundary = 1.0f / (float)len;   // IEEE divide; matches jnp 1/len
    return (ad >= boundary) ? v : 0.0f;
}

__device__ __forceinline__ float consume4(f32x4 o, f32x4 l, i32x4 n) {
    float s = 0.0f;
    s += sl1_term(o.x, l.x, n.x);
    s += sl1_term(o.y, l.y, n.y);
    s += sl1_term(o.z, l.z, n.z);
    s += sl1_term(o.w, l.w, n.w);
    return s;
}

__global__ __launch_bounds__(BLOCK, 2) void RegressionLoss_45440753992375_kernel(
        const float* __restrict__ outs,
        const float* __restrict__ labels,
        const int*   __restrict__ lens,
        float* __restrict__ out) {
    const f32x4* o4 = (const f32x4*)outs;
    const f32x4* l4 = (const f32x4*)labels;
    const i32x4* n4 = (const i32x4*)lens;

    // Block-contiguous 128KB span per array; thread strides BLOCK (4KB steps).
    const int base = blockIdx.x * (BLOCK * ITERS) + threadIdx.x;

    // Pipeline prologue: iterations 0..5 in flight (18 loads, 288B/thread).
    f32x4 oA = __builtin_nontemporal_load(o4 + base);
    f32x4 lA = __builtin_nontemporal_load(l4 + base);
    i32x4 nA = __builtin_nontemporal_load(n4 + base);

    f32x4 oB = __builtin_nontemporal_load(o4 + base + 1 * BLOCK);
    f32x4 lB = __builtin_nontemporal_load(l4 + base + 1 * BLOCK);
    i32x4 nB = __builtin_nontemporal_load(n4 + base + 1 * BLOCK);

    f32x4 oC = __builtin_nontemporal_load(o4 + base + 2 * BLOCK);
    f32x4 lC = __builtin_nontemporal_load(l4 + base + 2 * BLOCK);
    i32x4 nC = __builtin_nontemporal_load(n4 + base + 2 * BLOCK);

    f32x4 oD = __builtin_nontemporal_load(o4 + base + 3 * BLOCK);
    f32x4 lD = __builtin_nontemporal_load(l4 + base + 3 * BLOCK);
    i32x4 nD = __builtin_nontemporal_load(n4 + base + 3 * BLOCK);

    f32x4 oE = __builtin_nontemporal_load(o4 + base + 4 * BLOCK);
    f32x4 lE = __builtin_nontemporal_load(l4 + base + 4 * BLOCK);
    i32x4 nE = __builtin_nontemporal_load(n4 + base + 4 * BLOCK);

    f32x4 oF = __builtin_nontemporal_load(o4 + base + 5 * BLOCK);
    f32x4 lF = __builtin_nontemporal_load(l4 + base + 5 * BLOCK);
    i32x4 nF = __builtin_nontemporal_load(n4 + base + 5 * BLOCK);

    float acc = 0.0f;
    #pragma unroll
    for (int it = 0; it < ITERS - 6; ++it) {
        // Issue iteration it+6 (21 outstanding peak) before consuming it.
        const int idx = base + (it + 6) * BLOCK;
        f32x4 oG = __builtin_nontemporal_load(o4 + idx);
        f32x4 lG = __builtin_nontemporal_load(l4 + idx);
        i32x4 nG = __builtin_nontemporal_load(n4 + idx);

        acc += consume4(oA, lA, nA);

        // Rotate stages (register renaming; loop fully unrolled).
        oA = oB; lA = lB; nA = nB;
        oB = oC; lB = lC; nB = nC;
        oC = oD; lC = lD; nC = nD;
        oD = oE; lD = lE; nD = nE;
        oE = oF; lE = lF; nE = nF;
        oF = oG; lF = lG; nF = nG;
    }
    acc += consume4(oA, lA, nA);   // iteration ITERS-6
    acc += consume4(oB, lB, nB);   // iteration ITERS-5
    acc += consume4(oC, lC, nC);   // iteration ITERS-4
    acc += consume4(oD, lD, nD);   // iteration ITERS-3
    acc += consume4(oE, lE, nE);   // iteration ITERS-2
    acc += consume4(oF, lF, nF);   // iteration ITERS-1

    // wave-64 shuffle reduction
    #pragma unroll
    for (int off = 32; off > 0; off >>= 1)
        acc += __shfl_down(acc, off, 64);

    __shared__ float smem[BLOCK / 64];
    const int lane = threadIdx.x & 63;
    const int wid  = threadIdx.x >> 6;
    if (lane == 0) smem[wid] = acc;
    __syncthreads();
    if (threadIdx.x == 0) {
        float bsum = smem[0] + smem[1] + smem[2] + smem[3];
        atomicAdd(out, bsum);   // device-scope by default on CDNA
    }
}

extern "C" void kernel_launch(void* const* d_in, const int* in_sizes, int n_in,
                              void* d_out, int out_size, void* d_ws, size_t ws_size,
                              hipStream_t stream) {
    const float* outs   = (const float*)d_in[0];
    const float* labels = (const float*)d_in[1];
    const int*   lens   = (const int*)d_in[2];
    float* out = (float*)d_out;

    // d_out is poisoned 0xAA before every timed launch — zero it on-stream.
    hipMemsetAsync(out, 0, sizeof(float), stream);

    RegressionLoss_45440753992375_kernel<<<GRID, BLOCK, 0, stream>>>(outs, labels, lens, out);
}